// Round 6
// baseline (229.525 us; speedup 1.0000x reference)
//
#include <hip/hip_runtime.h>

// DCT compression: (32,3,512,512) fp32 -> (32,192,64,64) fp32
// Per 8x8 block: coef[a,u] = sum_{y,x} blk[y,x]*C8[a,y]*C8[u,x]
//   C8[u,y] = cos((u+0.5)*PI*y/8), PI = 3.1415 (module's approximation!)
// norm[a,u] = (a==0||u==0) ? sqrt(2)/8 : 0.25   (NOT separable: [0][0]=sqrt2/8)
// out[b, c*64 + z[a*8+u], hb, wb] = coef[a,u]*norm[a,u] / Qtab[c][z[a*8+u]]
//
// All tables (C8 cosines, zigzag, norm/Q scale) are constexpr -> no LDS, no
// __syncthreads, no serial prologue. VGPR_Count = 40 (measured R4).
//
// R4 counters showed latency-bound: Occupancy 44%, VALUBusy 17%, HBM 31%.
// Cause: single-wave workgroups hit the 16-WG/CU residency cap (16 waves/CU).
// Fix: 256-thread workgroups (grid 1536) -> at 40 VGPRs, 8 WGs/CU x 4 waves
// = 32 waves/CU (100% occupancy cap). No LDS/barrier, so block size is pure
// scheduling granularity. __launch_bounds__(256, 8) pins 8 waves/EU.

namespace {

// Compile-time cos: reduce to [-pi,pi] in double, 14-term Taylor (err ~1e-15),
// then round to float. Argument is computed with the exact fp32 expression the
// previously-verified kernel used on device: ((u+0.5f)*3.1415f)*(y*0.125f).
constexpr double ccos_d(double x) {
    while (x > 3.141592653589793) x -= 6.283185307179586;
    while (x < -3.141592653589793) x += 6.283185307179586;
    const double x2 = x * x;
    double t = 1.0, s = 1.0;
    for (int k = 1; k <= 14; ++k) {
        t *= -x2 / (double)((2 * k - 1) * (2 * k));
        s += t;
    }
    return s;
}

struct Tables {
    float c8[64];      // c8[u*8+y] = cos((u+0.5)*3.1415*y/8); c8[u*8+0] == 1.0f
    float scl[2][64];  // [luma/chroma][a*8+u] = norm(a,u)/Qtab[z(a,u)]
    int   zoff[64];    // z[a*8+u] * 4096  (output element offset)
};

constexpr Tables make_tables() {
    Tables T{};
    for (int u = 0; u < 8; ++u)
        for (int y = 0; y < 8; ++y) {
            const float arg = ((float)u + 0.5f) * 3.1415f * ((float)y * 0.125f);
            T.c8[u * 8 + y] = (float)ccos_d((double)arg);
        }
    // faithful port of reference _zigzag(8); p is the pre-transpose pattern
    int p[64] = {};
    for (int y = 0; y < 8; ++y)
        for (int x = (y & 1); x < 8 - y; x += 2) {
            const int v = x + y + 1;
            p[y * 8 + x] = v * (v + 1) / 2 - x - 1;
        }
    for (int y = 0; y < 8; ++y)
        for (int x = ((y + 1) & 1); x < 8 - y; x += 2) {
            const int v = x + y + 1;
            p[y * 8 + x] = v * (v + 1) / 2 - y - 1;
        }
    for (int y = 7; y >= 0; --y)
        for (int x = 7; x >= 8 - y; --x)
            p[y * 8 + x] = 63 - p[(7 - y) * 8 + (7 - x)];

    // Q=50 -> s=100 -> Q_luma = floor((100*T+50)/100) = T exactly (integers)
    const int QT0[64] = {16,11,10,16,24,40,51,61, 12,12,14,19,26,58,60,55,
                         14,13,16,24,40,57,69,56, 14,17,22,29,51,87,80,62,
                         18,22,37,56,68,109,103,77, 24,35,55,64,81,104,113,92,
                         49,64,78,87,103,121,120,101, 72,92,95,98,112,100,103,99};
    const int QT1[64] = {17,18,24,47,99,99,99,99, 18,21,26,66,99,99,99,99,
                         24,26,56,99,99,99,99,99, 47,66,99,99,99,99,99,99,
                         99,99,99,99,99,99,99,99, 99,99,99,99,99,99,99,99,
                         99,99,99,99,99,99,99,99, 99,99,99,99,99,99,99,99};
    for (int i = 0; i < 64; ++i) {
        const int a = i >> 3, u = i & 7;
        const int zi = p[u * 8 + a];  // z[a*8+u] = p.T[a][u] = p[u*8+a]
        T.zoff[i] = zi << 12;         // * 64*64
        const float nrm = (a == 0 || u == 0) ? 0.17677669529663687f : 0.25f;
        T.scl[0][i] = nrm / (float)QT0[zi];
        T.scl[1][i] = nrm / (float)QT1[zi];
    }
    return T;
}

constexpr Tables TB = make_tables();

}  // namespace

// Grid: 1536 workgroups of 256 threads.
//   blockIdx.x = bc*16 + hbg;  bc = b*3+c in [0,96);  hbg in [0,16)
//   wave (tid>>6) picks hb = hbg*4 + wave;  lane (tid&63) = wb.
// Each lane: one 8x8 block -> 64 outputs.
__global__ __launch_bounds__(256, 8)
void DCTCompression_25786983645730_kernel(const float* __restrict__ x,
                                          float* __restrict__ out) {
    const int tid = threadIdx.x;
    const int idx = blockIdx.x;
    const int hbg = idx & 15;
    const int bc  = idx >> 4;       // b*3 + c
    const int c   = bc % 3;         // wave-uniform

    const int wave = tid >> 6;
    const int wb   = tid & 63;
    const int hb   = hbg * 4 + wave;

    // uniform base + 32-bit lane offset -> saddr-form global loads/stores
    const float* xbase = x + (size_t)bc * 262144;
    float*       obase = out + (size_t)bc * 262144;
    const int    xo    = hb * 8 * 512 + wb * 8;
    const int    oo    = hb * 64 + wb;

    // ---- load 8x8 block: 16 independent float4 loads ----
    // (pairwise the two instructions cover each full 2KB image row)
    float4 r0[8], r1[8];
#pragma unroll
    for (int y = 0; y < 8; ++y) {
        r0[y] = *reinterpret_cast<const float4*>(xbase + xo + y * 512);
        r1[y] = *reinterpret_cast<const float4*>(xbase + xo + y * 512 + 4);
    }

    // ---- pass 1 (row transform): s[y][u] = sum_x blk[y][x] * C8[u][x] ----
    // consumes r0/r1 row-by-row; s replaces the block in registers
    float s[8][8];
#pragma unroll
    for (int y = 0; y < 8; ++y) {
        const float row[8] = {r0[y].x, r0[y].y, r0[y].z, r0[y].w,
                              r1[y].x, r1[y].y, r1[y].z, r1[y].w};
#pragma unroll
        for (int u = 0; u < 8; ++u) {
            float acc = row[0] * TB.c8[u * 8 + 0];  // c8[u][0]==1.0f -> folds
#pragma unroll
            for (int xx = 1; xx < 8; ++xx)
                acc = fmaf(row[xx], TB.c8[u * 8 + xx], acc);
            s[y][u] = acc;
        }
    }

    // ---- pass 2 (column transform), a-outer; scale + scatter per a ----
#pragma unroll
    for (int a = 0; a < 8; ++a) {
        float acc[8];
#pragma unroll
        for (int u = 0; u < 8; ++u) {
            float v = s[0][u] * TB.c8[a * 8 + 0];   // c8[a][0]==1.0f -> folds
#pragma unroll
            for (int y = 1; y < 8; ++y)
                v = fmaf(s[y][u], TB.c8[a * 8 + y], v);
            acc[u] = v;
        }
#pragma unroll
        for (int u = 0; u < 8; ++u) {
            const int j = a * 8 + u;
            const float sc = (c == 0) ? TB.scl[0][j] : TB.scl[1][j];  // scalar cselect
            obase[oo + TB.zoff[j]] = acc[u] * sc;  // coalesced 256B/wave store
        }
    }
}

extern "C" void kernel_launch(void* const* d_in, const int* in_sizes, int n_in,
                              void* d_out, int out_size, void* d_ws, size_t ws_size,
                              hipStream_t stream) {
    const float* x = (const float*)d_in[0];
    float* out = (float*)d_out;
    // B*C*(H/8/4) = 32*3*16 = 1536 workgroups of 256 threads
    DCTCompression_25786983645730_kernel<<<dim3(1536), dim3(256), 0, stream>>>(x, out);
}

// Round 7
// 175.928 us; speedup vs baseline: 1.3046x; 1.3046x over previous
//
#include <hip/hip_runtime.h>

// DCT compression: (32,3,512,512) fp32 -> (32,192,64,64) fp32
// Per 8x8 block: coef[a,u] = sum_{y,x} blk[y,x]*C8[a,y]*C8[u,x]
//   C8[u,y] = cos((u+0.5)*PI*y/8), PI = 3.1415 (module's approximation!)
// norm[a,u] = (a==0||u==0) ? sqrt(2)/8 : 0.25   (NOT separable: [0][0]=sqrt2/8)
// out[b, c*64 + z[a*8+u], hb, wb] = coef[a,u]*norm[a,u] / Qtab[c][z[a*8+u]]
//
// History (measured):
//   R4: 64-thr WGs, grid 6144, 1 blk/lane: 62 us, FETCH 50MB WRITE 98MB,
//       Occ 44%, VALU 17%  -> latency/store-efficiency bound, traffic clean.
//   R6: 256-thr WGs, grid 1536: 112 us, FETCH 155MB WRITE 204MB -> dispatch
//       shape amplified L2/L3 write traffic 2.1x. REVERTED to R4 geometry.
// This version: R4 shape + TWO vertically-adjacent blocks per lane (hb pair):
//   - 32 loads in flight per wave (2x MLP to hide ~900cyc HBM latency)
//   - stores issued as address-adjacent pairs: plane z gets rows hb0,hb0+1
//     (256B+256B contiguous) back-to-back -> 512B effective bursts, halving
//     DRAM page transitions of the 64-plane scatter.
// Grid 3072 single-wave WGs (12/CU, under the 16-WG/CU residency cap).
// ~150 VGPR peak (sA+sB live through pass 2); __launch_bounds__(64,3).

namespace {

// Compile-time cos: reduce to [-pi,pi] in double, 14-term Taylor (err ~1e-15),
// then round to float. Argument matches the verified device expression:
// ((u+0.5f)*3.1415f)*(y*0.125f).
constexpr double ccos_d(double x) {
    while (x > 3.141592653589793) x -= 6.283185307179586;
    while (x < -3.141592653589793) x += 6.283185307179586;
    const double x2 = x * x;
    double t = 1.0, s = 1.0;
    for (int k = 1; k <= 14; ++k) {
        t *= -x2 / (double)((2 * k - 1) * (2 * k));
        s += t;
    }
    return s;
}

struct Tables {
    float c8[64];      // c8[u*8+y] = cos((u+0.5)*3.1415*y/8); c8[u*8+0] == 1.0f
    float scl[2][64];  // [luma/chroma][a*8+u] = norm(a,u)/Qtab[z(a,u)]
    int   zoff[64];    // z[a*8+u] * 4096 (output element offset)
};

constexpr Tables make_tables() {
    Tables T{};
    for (int u = 0; u < 8; ++u)
        for (int y = 0; y < 8; ++y) {
            const float arg = ((float)u + 0.5f) * 3.1415f * ((float)y * 0.125f);
            T.c8[u * 8 + y] = (float)ccos_d((double)arg);
        }
    // faithful port of reference _zigzag(8); p is the pre-transpose pattern
    int p[64] = {};
    for (int y = 0; y < 8; ++y)
        for (int x = (y & 1); x < 8 - y; x += 2) {
            const int v = x + y + 1;
            p[y * 8 + x] = v * (v + 1) / 2 - x - 1;
        }
    for (int y = 0; y < 8; ++y)
        for (int x = ((y + 1) & 1); x < 8 - y; x += 2) {
            const int v = x + y + 1;
            p[y * 8 + x] = v * (v + 1) / 2 - y - 1;
        }
    for (int y = 7; y >= 0; --y)
        for (int x = 7; x >= 8 - y; --x)
            p[y * 8 + x] = 63 - p[(7 - y) * 8 + (7 - x)];

    // Q=50 -> s=100 -> Q_luma = floor((100*T+50)/100) = T exactly (integers)
    const int QT0[64] = {16,11,10,16,24,40,51,61, 12,12,14,19,26,58,60,55,
                         14,13,16,24,40,57,69,56, 14,17,22,29,51,87,80,62,
                         18,22,37,56,68,109,103,77, 24,35,55,64,81,104,113,92,
                         49,64,78,87,103,121,120,101, 72,92,95,98,112,100,103,99};
    const int QT1[64] = {17,18,24,47,99,99,99,99, 18,21,26,66,99,99,99,99,
                         24,26,56,99,99,99,99,99, 47,66,99,99,99,99,99,99,
                         99,99,99,99,99,99,99,99, 99,99,99,99,99,99,99,99,
                         99,99,99,99,99,99,99,99, 99,99,99,99,99,99,99,99};
    for (int i = 0; i < 64; ++i) {
        const int a = i >> 3, u = i & 7;
        const int zi = p[u * 8 + a];  // z[a*8+u] = p.T[a][u] = p[u*8+a]
        T.zoff[i] = zi << 12;         // * 64*64
        const float nrm = (a == 0 || u == 0) ? 0.17677669529663687f : 0.25f;
        T.scl[0][i] = nrm / (float)QT0[zi];
        T.scl[1][i] = nrm / (float)QT1[zi];
    }
    return T;
}

constexpr Tables TB = make_tables();

}  // namespace

// Grid: 3072 single-wave workgroups.
//   blockIdx.x = bc*32 + pr;  bc = b*3+c in [0,96);  pr in [0,32)
//   lane = wb.  Each lane: blocks (hb0,wb) and (hb0+1,wb), hb0 = pr*2.
__global__ __launch_bounds__(64, 3)
void DCTCompression_25786983645730_kernel(const float* __restrict__ x,
                                          float* __restrict__ out) {
    const int idx = blockIdx.x;
    const int pr  = idx & 31;
    const int bc  = idx >> 5;       // b*3 + c
    const int c   = bc % 3;         // wave-uniform
    const int wb  = threadIdx.x;    // 0..63
    const int hb0 = pr * 2;

    const float* xbase = x + (size_t)bc * 262144;
    float*       obase = out + (size_t)bc * 262144;
    const int    xoA   = hb0 * 4096 + wb * 8;   // block A top row
    const int    xoB   = xoA + 4096;            // block B top row (next 8 rows)
    const int    ooA   = hb0 * 64 + wb;         // output row hb0; hb0+1 at +64

    // ---- issue ALL 32 loads up front (2 blocks x 16 float4) ----
    float4 a0[8], a1[8], b0[8], b1[8];
#pragma unroll
    for (int y = 0; y < 8; ++y) {
        a0[y] = *reinterpret_cast<const float4*>(xbase + xoA + y * 512);
        a1[y] = *reinterpret_cast<const float4*>(xbase + xoA + y * 512 + 4);
    }
#pragma unroll
    for (int y = 0; y < 8; ++y) {
        b0[y] = *reinterpret_cast<const float4*>(xbase + xoB + y * 512);
        b1[y] = *reinterpret_cast<const float4*>(xbase + xoB + y * 512 + 4);
    }

    // ---- pass 1 for A: sA[y][u] = sum_x A[y][x] * C8[u][x] ----
    float sA[8][8];
#pragma unroll
    for (int y = 0; y < 8; ++y) {
        const float row[8] = {a0[y].x, a0[y].y, a0[y].z, a0[y].w,
                              a1[y].x, a1[y].y, a1[y].z, a1[y].w};
#pragma unroll
        for (int u = 0; u < 8; ++u) {
            float acc = row[0] * TB.c8[u * 8 + 0];  // c8[u][0]==1.0f -> folds
#pragma unroll
            for (int xx = 1; xx < 8; ++xx)
                acc = fmaf(row[xx], TB.c8[u * 8 + xx], acc);
            sA[y][u] = acc;
        }
    }

    // ---- pass 1 for B ----
    float sB[8][8];
#pragma unroll
    for (int y = 0; y < 8; ++y) {
        const float row[8] = {b0[y].x, b0[y].y, b0[y].z, b0[y].w,
                              b1[y].x, b1[y].y, b1[y].z, b1[y].w};
#pragma unroll
        for (int u = 0; u < 8; ++u) {
            float acc = row[0] * TB.c8[u * 8 + 0];
#pragma unroll
            for (int xx = 1; xx < 8; ++xx)
                acc = fmaf(row[xx], TB.c8[u * 8 + xx], acc);
            sB[y][u] = acc;
        }
    }

    // ---- pass 2 for both, a-outer; stores issued as adjacent (A,B) pairs:
    //      plane z receives rows hb0 and hb0+1 back-to-back (512B burst) ----
#pragma unroll
    for (int a = 0; a < 8; ++a) {
        float accA[8], accB[8];
#pragma unroll
        for (int u = 0; u < 8; ++u) {
            float vA = sA[0][u] * TB.c8[a * 8 + 0];  // c8[a][0]==1.0f -> folds
            float vB = sB[0][u] * TB.c8[a * 8 + 0];
#pragma unroll
            for (int y = 1; y < 8; ++y) {
                vA = fmaf(sA[y][u], TB.c8[a * 8 + y], vA);
                vB = fmaf(sB[y][u], TB.c8[a * 8 + y], vB);
            }
            accA[u] = vA;
            accB[u] = vB;
        }
#pragma unroll
        for (int u = 0; u < 8; ++u) {
            const int j = a * 8 + u;
            const float sc = (c == 0) ? TB.scl[0][j] : TB.scl[1][j];
            float* p = obase + ooA + TB.zoff[j];
            p[0]  = accA[u] * sc;   // row hb0   of plane z (256B/wave)
            p[64] = accB[u] * sc;   // row hb0+1 of plane z (next 256B)
        }
    }
}

extern "C" void kernel_launch(void* const* d_in, const int* in_sizes, int n_in,
                              void* d_out, int out_size, void* d_ws, size_t ws_size,
                              hipStream_t stream) {
    const float* x = (const float*)d_in[0];
    float* out = (float*)d_out;
    // B*C*(H/8/2) = 32*3*32 = 3072 single-wave workgroups
    DCTCompression_25786983645730_kernel<<<dim3(3072), dim3(64), 0, stream>>>(x, out);
}